// Round 16
// baseline (303.821 us; speedup 1.0000x reference)
//
#include <hip/hip_runtime.h>
#include <math.h>

#define N_NODES 100000
#define N_EDGES 600000
#define DIN     64
#define DH      128
#define NG      512
#define EPS_BN  1e-5f
#define SCAN_TPB 256
#define N_SCAN_BLK ((N_NODES + SCAN_TPB - 1) / SCAN_TPB)   // 391
#define G_EDGE   ((N_EDGES + 255) / 256)                   // 2344

typedef unsigned short u16;
typedef short s16x8 __attribute__((ext_vector_type(8)));
typedef float f32x4 __attribute__((ext_vector_type(4)));
typedef int   i32x4 __attribute__((ext_vector_type(4)));
typedef signed char s8x8 __attribute__((ext_vector_type(8)));

__device__ __forceinline__ u16 f2bf(float x) {
    unsigned u = __builtin_bit_cast(unsigned, x);
    u += 0x7fffu + ((u >> 16) & 1u);   // round-to-nearest-even
    return (u16)(u >> 16);
}
__device__ __forceinline__ float bf2f(u16 h) {
    unsigned u = ((unsigned)h) << 16;
    return __builtin_bit_cast(float, u);
}

// ---------------- fast zero of deg|cursor|done ----------------
#define ZERO_INTS (2 * N_NODES + 256)
__global__ __launch_bounds__(256) void zero_kernel(int* __restrict__ p) {
    const int i = (blockIdx.x * 256 + threadIdx.x) * 4;
    if (i < ZERO_INTS) *(i32x4*)(p + i) = i32x4{0, 0, 0, 0};
}

// ------- merged: degree histogram | Wt1..3 | bn fold | graph bounds -------
#define PREP_WT1_BLKS  32
#define PREP_WT2_BLKS  64
#define PREP_WT3_BLKS  64
#define PREP_BN_BLKS   2
#define PREP_GB_BLKS   3
#define PREP_B0 G_EDGE
#define PREP_B1 (PREP_B0 + PREP_WT1_BLKS)
#define PREP_B2 (PREP_B1 + PREP_WT2_BLKS)
#define PREP_B3 (PREP_B2 + PREP_WT3_BLKS)
#define PREP_B4 (PREP_B3 + PREP_BN_BLKS)
#define PREP_TOTAL (PREP_B4 + PREP_GB_BLKS)

__device__ __forceinline__ void wt_body(const float* __restrict__ W, u16* __restrict__ Wt,
                                        int K, int idx) {
    if (idx >= K * DH) return;
    int k = idx / DH, n = idx % DH;
    Wt[(long)n * K + k] = f2bf(W[idx]);
}

__global__ __launch_bounds__(256) void degprep_kernel(
    const int* __restrict__ dst, int* __restrict__ deg,
    const float* __restrict__ W1, u16* __restrict__ Wt1,
    const float* __restrict__ W2, u16* __restrict__ Wt2,
    const float* __restrict__ W3, u16* __restrict__ Wt3,
    const float* b1, const float* g1, const float* bb1, const float* m1, const float* v1,
    const float* b2, const float* g2, const float* bb2, const float* m2, const float* v2,
    const float* b3, const float* g3, const float* bb3, const float* m3, const float* v3,
    float* __restrict__ sc, float* __restrict__ sh,
    const int* __restrict__ batch, int* __restrict__ gp) {
    const int b = blockIdx.x;
    const int tid = threadIdx.x;
    if (b < PREP_B0) {
        const int e = b * 256 + tid;
        if (e < N_EDGES) atomicAdd(&deg[dst[e]], 1);
    } else if (b < PREP_B1) {
        wt_body(W1, Wt1, DIN, (b - PREP_B0) * 256 + tid);
    } else if (b < PREP_B2) {
        wt_body(W2, Wt2, DH, (b - PREP_B1) * 256 + tid);
    } else if (b < PREP_B3) {
        wt_body(W3, Wt3, DH, (b - PREP_B2) * 256 + tid);
    } else if (b < PREP_B4) {
        const int i = (b - PREP_B3) * 256 + tid;
        if (i < 3 * DH) {
            int l = i >> 7, c = i & (DH - 1);
            const float* bc = l == 0 ? b1 : (l == 1 ? b2 : b3);
            const float* g  = l == 0 ? g1 : (l == 1 ? g2 : g3);
            const float* bb = l == 0 ? bb1 : (l == 1 ? bb2 : bb3);
            const float* m  = l == 0 ? m1 : (l == 1 ? m2 : m3);
            const float* v  = l == 0 ? v1 : (l == 1 ? v2 : v3);
            float s = g[c] * rsqrtf(v[c] + EPS_BN);
            sc[i] = s;
            sh[i] = (bc[c] - m[c]) * s + bb[c];
        }
    } else {
        const int g = (b - PREP_B4) * 256 + tid;
        if (g <= NG) {
            int lo = 0, hi = N_NODES;
            while (lo < hi) {
                int mid = (lo + hi) >> 1;
                if (batch[mid] < g) lo = mid + 1; else hi = mid;
            }
            gp[g] = lo;
        }
    }
}

// --- single-pass scan: local prefix + block sums; last-done block scans the block sums ---
__global__ __launch_bounds__(SCAN_TPB) void scan_kernel(const int* __restrict__ deg,
                                                        float* __restrict__ dis,
                                                        int* __restrict__ rp,
                                                        int* __restrict__ blk,
                                                        int* __restrict__ done, int n) {
    __shared__ int sm[SCAN_TPB];
    __shared__ int sflag;
    const int t = threadIdx.x;
    const int i = blockIdx.x * SCAN_TPB + t;
    int v = 0;
    if (i < n) {
        v = deg[i];
        dis[i] = rsqrtf((float)v + 1.0f);   // +1 self loop
    }
    sm[t] = v;
    __syncthreads();
#pragma unroll
    for (int off = 1; off < SCAN_TPB; off <<= 1) {
        int u = (t >= off) ? sm[t - off] : 0;
        __syncthreads();
        sm[t] += u;
        __syncthreads();
    }
    if (i <= n) rp[i] = sm[t] - v;            // local exclusive prefix
    if (t == SCAN_TPB - 1) blk[blockIdx.x] = sm[t];

    __syncthreads();
    if (t == 0) {
        __threadfence();
        const int r = atomicAdd(done, 1);
        sflag = (r == (int)gridDim.x - 1);
    }
    __syncthreads();
    if (!sflag) return;

    int a0 = (2 * t < N_SCAN_BLK)
                 ? __hip_atomic_load(&blk[2 * t], __ATOMIC_RELAXED, __HIP_MEMORY_SCOPE_AGENT)
                 : 0;
    int a1 = (2 * t + 1 < N_SCAN_BLK)
                 ? __hip_atomic_load(&blk[2 * t + 1], __ATOMIC_RELAXED, __HIP_MEMORY_SCOPE_AGENT)
                 : 0;
    const int s = a0 + a1;
    sm[t] = s;
    __syncthreads();
#pragma unroll
    for (int off = 1; off < SCAN_TPB; off <<= 1) {
        int u = (t >= off) ? sm[t - off] : 0;
        __syncthreads();
        sm[t] += u;
        __syncthreads();
    }
    const int ex = sm[t] - s;
    if (2 * t < N_SCAN_BLK) blk[2 * t] = ex;
    if (2 * t + 1 < N_SCAN_BLK) blk[2 * t + 1] = ex + a0;
}

// ---- merged: scatter edges into CSR (col only) | xcvt xb = bf16(x * dis[row]) ----
#define CSRX_XCVT_BLKS 3125
#define CSRX_TOTAL (G_EDGE + CSRX_XCVT_BLKS)
__global__ __launch_bounds__(256) void csr_xcvt_kernel(const int* __restrict__ src,
                                                       const int* __restrict__ dst,
                                                       const int* __restrict__ rp,
                                                       const int* __restrict__ blk,
                                                       int* __restrict__ cursor,
                                                       int* __restrict__ col,
                                                       const float* __restrict__ x,
                                                       const float* __restrict__ dis,
                                                       u16* __restrict__ xb) {
    const int b = blockIdx.x;
    const int tid = threadIdx.x;
    if (b < G_EDGE) {
        const int e = b * 256 + tid;
        if (e >= N_EDGES) return;
        const int s = src[e];
        const int d = dst[e];
        const int p = atomicAdd(&cursor[d], 1);
        col[rp[d] + blk[d >> 8] + p] = s;
    } else {
        const long base = ((long)(b - G_EDGE) * 256 + tid) * 8;
        const float dd = dis[base >> 6];
        const float4 a = *(const float4*)(x + base);
        const float4 c = *(const float4*)(x + base + 4);
        s16x8 o;
        o[0] = (short)f2bf(a.x * dd); o[1] = (short)f2bf(a.y * dd);
        o[2] = (short)f2bf(a.z * dd); o[3] = (short)f2bf(a.w * dd);
        o[4] = (short)f2bf(c.x * dd); o[5] = (short)f2bf(c.y * dd);
        o[6] = (short)f2bf(c.z * dd); o[7] = (short)f2bf(c.w * dd);
        *(s16x8*)(xb + base) = o;
    }
}

// ---- layer-1 aggregate in 64-dim input space ----
__global__ __launch_bounds__(256) void agg64_kernel(const u16* __restrict__ xb,
                                                    const int* __restrict__ rp,
                                                    const int* __restrict__ blk,
                                                    const int* __restrict__ col,
                                                    const float* __restrict__ dis,
                                                    u16* __restrict__ aggX, int n) {
    const long t = (long)blockIdx.x * blockDim.x + threadIdx.x;
    const int lane = (int)(t & 31);
    const long i = t >> 5;
    if (i >= n) return;
    const int cl = lane & 7;
    const int eh = (lane >> 3) & 3;
    const int c = cl * 8;

    float acc[8] = {0, 0, 0, 0, 0, 0, 0, 0};
    if (eh == 0) {
        const s16x8 hv = *(const s16x8*)(xb + i * DIN + c);
#pragma unroll
        for (int q = 0; q < 8; ++q) acc[q] = bf2f((u16)hv[q]);
    }

    const int beg = rp[i] + blk[i >> 8];
    const int end = rp[i + 1] + blk[(int)(i + 1) >> 8];
    int e = beg + eh;
    if (e < end) {
        int s = col[e];
        s16x8 v = *(const s16x8*)(xb + (long)s * DIN + c);
        e += 4;
        for (; e < end; e += 4) {
            const int s2 = col[e];                                // prefetch next
            const s16x8 v2 = *(const s16x8*)(xb + (long)s2 * DIN + c);
#pragma unroll
            for (int q = 0; q < 8; ++q) acc[q] += bf2f((u16)v[q]); // consume current
            v = v2;
        }
#pragma unroll
        for (int q = 0; q < 8; ++q) acc[q] += bf2f((u16)v[q]);
    }

#pragma unroll
    for (int q = 0; q < 8; ++q) acc[q] += __shfl_xor(acc[q], 8);
#pragma unroll
    for (int q = 0; q < 8; ++q) acc[q] += __shfl_xor(acc[q], 16);

    if (eh == 0 && (lane >> 4) == 0) {
        const float dd = dis[i];
        s16x8 ov;
#pragma unroll
        for (int q = 0; q < 8; ++q) ov[q] = (short)f2bf(acc[q] * dd);
        *(s16x8*)(aggX + i * DIN + c) = ov;
    }
}

// ---- MFMA GEMM. Epilogue: BN+ReLU->bf16 (layer1) OR dis-scale->int8+rowscale (layers 2/3) ----
template <int K, bool BN_EPI, bool QOUT>
__global__ __launch_bounds__(256) void gemm_mfma(const u16* __restrict__ A,   // [M][K]
                                                 const u16* __restrict__ Wt,  // [128][K]
                                                 const float* __restrict__ dis,
                                                 const float* __restrict__ scl,
                                                 const float* __restrict__ shf,
                                                 u16* __restrict__ C,         // bf16 out
                                                 signed char* __restrict__ Cq,// int8 out
                                                 float* __restrict__ qsc,     // row scales
                                                 int M) {
    __shared__ u16 ldsc[4][16][DH];
    const int wave = threadIdx.x >> 6;
    const int lane = threadIdx.x & 63;
    const int r16 = lane & 15;
    const int kc  = lane >> 4;
    const long row0 = (long)blockIdx.x * 64 + wave * 16;

    f32x4 acc[8];
#pragma unroll
    for (int t = 0; t < 8; ++t)
#pragma unroll
        for (int q = 0; q < 4; ++q) acc[t][q] = 0.0f;

    long arow = row0 + r16;
    if (arow >= M) arow = M - 1;

#pragma unroll
    for (int ks = 0; ks < K; ks += 32) {
        const s16x8 a = *(const s16x8*)(A + arow * K + ks + kc * 8);
#pragma unroll
        for (int t = 0; t < 8; ++t) {
            const s16x8 b = *(const s16x8*)(Wt + (long)(t * 16 + r16) * K + ks + kc * 8);
            acc[t] = __builtin_amdgcn_mfma_f32_16x16x32_bf16(a, b, acc[t], 0, 0, 0);
        }
    }

    float dd[4], scv[8], shv[8];
    if constexpr (BN_EPI) {
#pragma unroll
        for (int t = 0; t < 8; ++t) {
            scv[t] = scl[t * 16 + r16];
            shv[t] = shf[t * 16 + r16];
        }
    } else {
#pragma unroll
        for (int q = 0; q < 4; ++q) {
            long r = row0 + kc * 4 + q;
            dd[q] = dis[r < M ? r : (M - 1)];
        }
    }

    // stage to LDS, swizzled 16B blocks
#pragma unroll
    for (int t = 0; t < 8; ++t) {
        const int blkc = (t << 1) | (r16 >> 3);
        const int co = r16 & 7;
#pragma unroll
        for (int q = 0; q < 4; ++q) {
            const int row = kc * 4 + q;
            float y;
            if constexpr (BN_EPI) {
                y = fmaxf(fmaf(acc[t][q], scv[t], shv[t]), 0.0f);
            } else {
                y = acc[t][q] * dd[q];
            }
            ldsc[wave][row][(((blkc ^ (row & 7)) << 3) | co)] = f2bf(y);
        }
    }
    // read back rows coalesced; same-wave producer/consumer
#pragma unroll
    for (int it = 0; it < 4; ++it) {
        const int rl = (lane >> 4) + it * 4;
        const long row = row0 + rl;
        const int phys = (lane & 15) ^ (rl & 7);
        const s16x8 v = *(const s16x8*)&ldsc[wave][rl][phys << 3];
        if constexpr (QOUT) {
            float f[8], m = 0.0f;
#pragma unroll
            for (int q = 0; q < 8; ++q) {
                f[q] = bf2f((u16)v[q]);
                m = fmaxf(m, fabsf(f[q]));
            }
            m = fmaxf(m, __shfl_xor(m, 1));
            m = fmaxf(m, __shfl_xor(m, 2));
            m = fmaxf(m, __shfl_xor(m, 4));
            m = fmaxf(m, __shfl_xor(m, 8));
            const float inv = (m > 0.0f) ? 127.0f / m : 0.0f;
            s8x8 o;
#pragma unroll
            for (int q = 0; q < 8; ++q) o[q] = (signed char)(int)rintf(f[q] * inv);
            if (row < M) {
                *(s8x8*)(Cq + row * DH + ((lane & 15) << 3)) = o;
                if ((lane & 15) == 0) qsc[row] = m * (1.0f / 127.0f);
            }
        } else {
            if (row < M) *(s16x8*)(C + row * DH + ((lane & 15) << 3)) = v;
        }
    }
}

// ---- fused agg (int8, dequant): 1 WAVE PER NODE, 4 edge slots x 16 ch-lanes,
// ---- 2-deep software pipeline (next col/row/scale issued before current consume) ----
template <bool RES>
__global__ __launch_bounds__(256) void agg_epi_q8_kernel(const signed char* __restrict__ Hq,
                                                         const float* __restrict__ qsc,
                                                         const int* __restrict__ rp,
                                                         const int* __restrict__ blk,
                                                         const int* __restrict__ col,
                                                         const float* __restrict__ dis,
                                                         const float* __restrict__ scl,
                                                         const float* __restrict__ shf,
                                                         u16* __restrict__ out, int n) {
    const long t = (long)blockIdx.x * blockDim.x + threadIdx.x;
    const int lane = (int)(t & 63);
    const long i = t >> 6;          // one wave per node
    if (i >= n) return;
    const int cl = lane & 15;
    const int eh = lane >> 4;       // 0..3 edge slot
    const int c = cl * 8;

    float acc[8] = {0, 0, 0, 0, 0, 0, 0, 0};
    if (eh == 0) {   // self row (already dis[i]-scaled in gemm, int8)
        const s8x8 hv = *(const s8x8*)(Hq + i * DH + c);
        const float hs = qsc[i];
#pragma unroll
        for (int q = 0; q < 8; ++q) acc[q] = (float)hv[q] * hs;
    }

    const int beg = rp[i] + blk[i >> 8];
    const int end = rp[i + 1] + blk[(int)(i + 1) >> 8];
    int e = beg + eh;
    if (e < end) {
        int s = col[e];
        s8x8 v = *(const s8x8*)(Hq + (long)s * DH + c);
        float ss = qsc[s];
        e += 4;
        for (; e < end; e += 4) {
            const int s2 = col[e];                                    // issue next
            const s8x8 v2 = *(const s8x8*)(Hq + (long)s2 * DH + c);
            const float ss2 = qsc[s2];
#pragma unroll
            for (int q = 0; q < 8; ++q) acc[q] = fmaf((float)v[q], ss, acc[q]);
            v = v2; ss = ss2;
        }
#pragma unroll
        for (int q = 0; q < 8; ++q) acc[q] = fmaf((float)v[q], ss, acc[q]);
    }

    // reduce across the 4 edge slots
#pragma unroll
    for (int q = 0; q < 8; ++q) acc[q] += __shfl_xor(acc[q], 16);
#pragma unroll
    for (int q = 0; q < 8; ++q) acc[q] += __shfl_xor(acc[q], 32);

    if (eh == 0) {
        const float dd = dis[i];
        const float4 s0 = *(const float4*)(scl + c);
        const float4 s1 = *(const float4*)(scl + c + 4);
        const float4 f0 = *(const float4*)(shf + c);
        const float4 f1 = *(const float4*)(shf + c + 4);
        const float sv[8] = {s0.x, s0.y, s0.z, s0.w, s1.x, s1.y, s1.z, s1.w};
        const float fv[8] = {f0.x, f0.y, f0.z, f0.w, f1.x, f1.y, f1.z, f1.w};

        float r[8];
#pragma unroll
        for (int q = 0; q < 8; ++q) r[q] = fmaxf(fmaf(acc[q] * dd, sv[q], fv[q]), 0.0f);
        if (RES) {
            const s16x8 rv = *(const s16x8*)(out + i * DH + c);
#pragma unroll
            for (int q = 0; q < 8; ++q) r[q] += bf2f((u16)rv[q]);
        }
        s16x8 ov;
#pragma unroll
        for (int q = 0; q < 8; ++q) ov[q] = (short)f2bf(r[q]);
        __builtin_nontemporal_store(ov, (s16x8*)(out + i * DH + c));
    }
}

// ------- fused mean-pool + MLP head: 1 block/graph -------
__global__ __launch_bounds__(256) void pool_head_kernel(const u16* __restrict__ h,
                                                        const int* __restrict__ gp,
                                                        const float* __restrict__ fc1w,
                                                        const float* __restrict__ fc1b,
                                                        const float* __restrict__ fc2w,
                                                        const float* __restrict__ fc2b,
                                                        float* __restrict__ out) {
    const int g = blockIdx.x;
    const int t = threadIdx.x;
    const int grp = t >> 4;
    const int cl = t & 15;
    const int c = cl * 8;
    const int beg = gp[g];
    const int end = gp[g + 1];

    float acc[8] = {0, 0, 0, 0, 0, 0, 0, 0};
    for (int i = beg + grp; i < end; i += 16) {
        const s16x8 v = *(const s16x8*)(h + (long)i * DH + c);
#pragma unroll
        for (int q = 0; q < 8; ++q) acc[q] += bf2f((u16)v[q]);
    }

    __shared__ float sm[16][DH];
    __shared__ float p[DH];
#pragma unroll
    for (int q = 0; q < 8; ++q) sm[grp][c + q] = acc[q];
    __syncthreads();

    if (t < DH) {
        float s = 0.0f;
#pragma unroll
        for (int r = 0; r < 16; ++r) s += sm[r][t];
        p[t] = s / fmaxf((float)(end - beg), 1.0f);
    }
    __syncthreads();

    if (t < 64) {
        float a = 0.0f;
#pragma unroll 4
        for (int k = 0; k < DH; ++k) a = fmaf(p[k], fc1w[(long)k * 64 + t], a);
        const float h1 = fmaxf(a + fc1b[t], 0.0f);
        float v = h1 * fc2w[t];
#pragma unroll
        for (int off = 32; off > 0; off >>= 1) v += __shfl_down(v, off);
        if (t == 0) out[g] = 1.0f / (1.0f + expf(-(v + fc2b[0])));
    }
}

// ---------------- launch ----------------
extern "C" void kernel_launch(void* const* d_in, const int* in_sizes, int n_in,
                              void* d_out, int out_size, void* d_ws, size_t ws_size,
                              hipStream_t stream) {
    const float* x     = (const float*)d_in[0];
    const int*   ei    = (const int*)d_in[1];
    const int*   batch = (const int*)d_in[2];
    const float* W1 = (const float*)d_in[3];
    const float* b1 = (const float*)d_in[4];
    const float* g1 = (const float*)d_in[5];
    const float* t1 = (const float*)d_in[6];
    const float* m1 = (const float*)d_in[7];
    const float* v1 = (const float*)d_in[8];
    const float* W2 = (const float*)d_in[9];
    const float* b2 = (const float*)d_in[10];
    const float* g2 = (const float*)d_in[11];
    const float* t2 = (const float*)d_in[12];
    const float* m2 = (const float*)d_in[13];
    const float* v2 = (const float*)d_in[14];
    const float* W3 = (const float*)d_in[15];
    const float* b3 = (const float*)d_in[16];
    const float* g3 = (const float*)d_in[17];
    const float* t3 = (const float*)d_in[18];
    const float* m3 = (const float*)d_in[19];
    const float* v3 = (const float*)d_in[20];
    const float* fc1w = (const float*)d_in[21];
    const float* fc1b = (const float*)d_in[22];
    const float* fc2w = (const float*)d_in[23];
    const float* fc2b = (const float*)d_in[24];

    const int* src = ei;
    const int* dst = ei + N_EDGES;

    // ---- workspace ----
    char* ws = (char*)d_ws;
    size_t off = 0;
    auto alloc = [&](size_t bytes) -> char* {
        char* p = ws + off;
        off = (off + bytes + 511) & ~(size_t)511;
        return p;
    };
    int*   deg     = (int*)  alloc((size_t)ZERO_INTS * 4);
    int*   cursor  = deg + N_NODES;
    int*   done    = deg + 2 * N_NODES;
    float* dis     = (float*)alloc((size_t)N_NODES * 4);
    int*   rp      = (int*)  alloc(((size_t)N_NODES + 1) * 4);
    int*   blk     = (int*)  alloc((size_t)N_SCAN_BLK * 4);
    int*   col     = (int*)  alloc((size_t)N_EDGES * 4);
    int*   gp      = (int*)  alloc((size_t)(NG + 1) * 4);
    float* bnsc    = (float*)alloc((size_t)3 * DH * 4);
    float* bnsh    = (float*)alloc((size_t)3 * DH * 4);
    u16*   Wt1     = (u16*)  alloc((size_t)DH * DIN * 2);
    u16*   Wt2     = (u16*)  alloc((size_t)DH * DH * 2);
    u16*   Wt3     = (u16*)  alloc((size_t)DH * DH * 2);
    u16*   xb      = (u16*)  alloc((size_t)N_NODES * DIN * 2);
    u16*   aggX    = (u16*)  alloc((size_t)N_NODES * DIN * 2);
    signed char* bufQ = (signed char*)alloc((size_t)N_NODES * DH);
    float* qscale  = (float*)alloc((size_t)N_NODES * 4);
    u16*   bufA    = (u16*)  alloc((size_t)N_NODES * DH * 2);

    const int TPB = 256;
    const int gZero = (ZERO_INTS / 4 + TPB - 1) / TPB;
    const int gGemm = (N_NODES + 63) / 64;
    const int gAgg32 = (int)(((long)N_NODES * 32 + TPB - 1) / TPB);     // 12500
    const int gAgg64 = (int)(((long)N_NODES * 64 + TPB - 1) / TPB);     // 25000

    // ---- prep ----
    zero_kernel<<<gZero, TPB, 0, stream>>>(deg);
    degprep_kernel<<<PREP_TOTAL, TPB, 0, stream>>>(dst, deg, W1, Wt1, W2, Wt2, W3, Wt3,
                                                   b1, g1, t1, m1, v1,
                                                   b2, g2, t2, m2, v2,
                                                   b3, g3, t3, m3, v3,
                                                   bnsc, bnsh, batch, gp);
    scan_kernel<<<N_SCAN_BLK, SCAN_TPB, 0, stream>>>(deg, dis, rp, blk, done, N_NODES);
    csr_xcvt_kernel<<<CSRX_TOTAL, TPB, 0, stream>>>(src, dst, rp, blk, cursor, col,
                                                    x, dis, xb);

    // ---- layer 1: aggregate in 64-dim, then GEMM with BN+ReLU epilogue (bf16 out) ----
    agg64_kernel<<<gAgg32, TPB, 0, stream>>>(xb, rp, blk, col, dis, aggX, N_NODES);
    gemm_mfma<DIN, true, false><<<gGemm, TPB, 0, stream>>>(aggX, Wt1, dis, bnsc, bnsh,
                                                           bufA, nullptr, nullptr, N_NODES);
    // ---- layer 2: GEMM -> int8+rowscale; gather-agg dequant (residual into bufA) ----
    gemm_mfma<DH, false, true><<<gGemm, TPB, 0, stream>>>(bufA, Wt2, dis, nullptr, nullptr,
                                                          nullptr, bufQ, qscale, N_NODES);
    agg_epi_q8_kernel<true><<<gAgg64, TPB, 0, stream>>>(bufQ, qscale, rp, blk, col, dis,
                                                        bnsc + DH, bnsh + DH, bufA, N_NODES);
    // ---- layer 3 ----
    gemm_mfma<DH, false, true><<<gGemm, TPB, 0, stream>>>(bufA, Wt3, dis, nullptr, nullptr,
                                                          nullptr, bufQ, qscale, N_NODES);
    agg_epi_q8_kernel<false><<<gAgg64, TPB, 0, stream>>>(bufQ, qscale, rp, blk, col, dis,
                                                         bnsc + 2 * DH, bnsh + 2 * DH, bufA,
                                                         N_NODES);

    // ---- pool + head (fused) ----
    pool_head_kernel<<<NG, TPB, 0, stream>>>(bufA, gp, fc1w, fc1b, fc2w, fc2b,
                                             (float*)d_out);
}

// Round 17
// 294.414 us; speedup vs baseline: 1.0320x; 1.0320x over previous
//
#include <hip/hip_runtime.h>
#include <math.h>

#define N_NODES 100000
#define N_EDGES 600000
#define DIN     64
#define DH      128
#define NG      512
#define EPS_BN  1e-5f
#define SCAN_TPB 256
#define N_SCAN_BLK ((N_NODES + SCAN_TPB - 1) / SCAN_TPB)   // 391
#define G_EDGE   ((N_EDGES + 255) / 256)                   // 2344

typedef unsigned short u16;
typedef short s16x8 __attribute__((ext_vector_type(8)));
typedef float f32x4 __attribute__((ext_vector_type(4)));
typedef int   i32x4 __attribute__((ext_vector_type(4)));
typedef signed char s8x8 __attribute__((ext_vector_type(8)));

__device__ __forceinline__ u16 f2bf(float x) {
    unsigned u = __builtin_bit_cast(unsigned, x);
    u += 0x7fffu + ((u >> 16) & 1u);   // round-to-nearest-even
    return (u16)(u >> 16);
}
__device__ __forceinline__ float bf2f(u16 h) {
    unsigned u = ((unsigned)h) << 16;
    return __builtin_bit_cast(float, u);
}

// ---------------- fast zero of deg|cursor|done ----------------
#define ZERO_INTS (2 * N_NODES + 256)
__global__ __launch_bounds__(256) void zero_kernel(int* __restrict__ p) {
    const int i = (blockIdx.x * 256 + threadIdx.x) * 4;
    if (i < ZERO_INTS) *(i32x4*)(p + i) = i32x4{0, 0, 0, 0};
}

// ------- merged: degree histogram | Wt1..3 | bn fold | graph bounds -------
#define PREP_WT1_BLKS  32
#define PREP_WT2_BLKS  64
#define PREP_WT3_BLKS  64
#define PREP_BN_BLKS   2
#define PREP_GB_BLKS   3
#define PREP_B0 G_EDGE
#define PREP_B1 (PREP_B0 + PREP_WT1_BLKS)
#define PREP_B2 (PREP_B1 + PREP_WT2_BLKS)
#define PREP_B3 (PREP_B2 + PREP_WT3_BLKS)
#define PREP_B4 (PREP_B3 + PREP_BN_BLKS)
#define PREP_TOTAL (PREP_B4 + PREP_GB_BLKS)

__device__ __forceinline__ void wt_body(const float* __restrict__ W, u16* __restrict__ Wt,
                                        int K, int idx) {
    if (idx >= K * DH) return;
    int k = idx / DH, n = idx % DH;
    Wt[(long)n * K + k] = f2bf(W[idx]);
}

__global__ __launch_bounds__(256) void degprep_kernel(
    const int* __restrict__ dst, int* __restrict__ deg,
    const float* __restrict__ W1, u16* __restrict__ Wt1,
    const float* __restrict__ W2, u16* __restrict__ Wt2,
    const float* __restrict__ W3, u16* __restrict__ Wt3,
    const float* b1, const float* g1, const float* bb1, const float* m1, const float* v1,
    const float* b2, const float* g2, const float* bb2, const float* m2, const float* v2,
    const float* b3, const float* g3, const float* bb3, const float* m3, const float* v3,
    float* __restrict__ sc, float* __restrict__ sh,
    const int* __restrict__ batch, int* __restrict__ gp) {
    const int b = blockIdx.x;
    const int tid = threadIdx.x;
    if (b < PREP_B0) {
        const int e = b * 256 + tid;
        if (e < N_EDGES) atomicAdd(&deg[dst[e]], 1);
    } else if (b < PREP_B1) {
        wt_body(W1, Wt1, DIN, (b - PREP_B0) * 256 + tid);
    } else if (b < PREP_B2) {
        wt_body(W2, Wt2, DH, (b - PREP_B1) * 256 + tid);
    } else if (b < PREP_B3) {
        wt_body(W3, Wt3, DH, (b - PREP_B2) * 256 + tid);
    } else if (b < PREP_B4) {
        const int i = (b - PREP_B3) * 256 + tid;
        if (i < 3 * DH) {
            int l = i >> 7, c = i & (DH - 1);
            const float* bc = l == 0 ? b1 : (l == 1 ? b2 : b3);
            const float* g  = l == 0 ? g1 : (l == 1 ? g2 : g3);
            const float* bb = l == 0 ? bb1 : (l == 1 ? bb2 : bb3);
            const float* m  = l == 0 ? m1 : (l == 1 ? m2 : m3);
            const float* v  = l == 0 ? v1 : (l == 1 ? v2 : v3);
            float s = g[c] * rsqrtf(v[c] + EPS_BN);
            sc[i] = s;
            sh[i] = (bc[c] - m[c]) * s + bb[c];
        }
    } else {
        const int g = (b - PREP_B4) * 256 + tid;
        if (g <= NG) {
            int lo = 0, hi = N_NODES;
            while (lo < hi) {
                int mid = (lo + hi) >> 1;
                if (batch[mid] < g) lo = mid + 1; else hi = mid;
            }
            gp[g] = lo;
        }
    }
}

// --- single-pass scan: local prefix + block sums; last-done block scans the block sums ---
__global__ __launch_bounds__(SCAN_TPB) void scan_kernel(const int* __restrict__ deg,
                                                        float* __restrict__ dis,
                                                        int* __restrict__ rp,
                                                        int* __restrict__ blk,
                                                        int* __restrict__ done, int n) {
    __shared__ int sm[SCAN_TPB];
    __shared__ int sflag;
    const int t = threadIdx.x;
    const int i = blockIdx.x * SCAN_TPB + t;
    int v = 0;
    if (i < n) {
        v = deg[i];
        dis[i] = rsqrtf((float)v + 1.0f);   // +1 self loop
    }
    sm[t] = v;
    __syncthreads();
#pragma unroll
    for (int off = 1; off < SCAN_TPB; off <<= 1) {
        int u = (t >= off) ? sm[t - off] : 0;
        __syncthreads();
        sm[t] += u;
        __syncthreads();
    }
    if (i <= n) rp[i] = sm[t] - v;            // local exclusive prefix
    if (t == SCAN_TPB - 1) blk[blockIdx.x] = sm[t];

    __syncthreads();
    if (t == 0) {
        __threadfence();
        const int r = atomicAdd(done, 1);
        sflag = (r == (int)gridDim.x - 1);
    }
    __syncthreads();
    if (!sflag) return;

    int a0 = (2 * t < N_SCAN_BLK)
                 ? __hip_atomic_load(&blk[2 * t], __ATOMIC_RELAXED, __HIP_MEMORY_SCOPE_AGENT)
                 : 0;
    int a1 = (2 * t + 1 < N_SCAN_BLK)
                 ? __hip_atomic_load(&blk[2 * t + 1], __ATOMIC_RELAXED, __HIP_MEMORY_SCOPE_AGENT)
                 : 0;
    const int s = a0 + a1;
    sm[t] = s;
    __syncthreads();
#pragma unroll
    for (int off = 1; off < SCAN_TPB; off <<= 1) {
        int u = (t >= off) ? sm[t - off] : 0;
        __syncthreads();
        sm[t] += u;
        __syncthreads();
    }
    const int ex = sm[t] - s;
    if (2 * t < N_SCAN_BLK) blk[2 * t] = ex;
    if (2 * t + 1 < N_SCAN_BLK) blk[2 * t + 1] = ex + a0;
}

// ---- merged: scatter edges into CSR (col only) | xcvt xb = bf16(x * dis[row]) ----
#define CSRX_XCVT_BLKS 3125
#define CSRX_TOTAL (G_EDGE + CSRX_XCVT_BLKS)
__global__ __launch_bounds__(256) void csr_xcvt_kernel(const int* __restrict__ src,
                                                       const int* __restrict__ dst,
                                                       const int* __restrict__ rp,
                                                       const int* __restrict__ blk,
                                                       int* __restrict__ cursor,
                                                       int* __restrict__ col,
                                                       const float* __restrict__ x,
                                                       const float* __restrict__ dis,
                                                       u16* __restrict__ xb) {
    const int b = blockIdx.x;
    const int tid = threadIdx.x;
    if (b < G_EDGE) {
        const int e = b * 256 + tid;
        if (e >= N_EDGES) return;
        const int s = src[e];
        const int d = dst[e];
        const int p = atomicAdd(&cursor[d], 1);
        __builtin_nontemporal_store(s, &col[rp[d] + blk[d >> 8] + p]);
    } else {
        const long base = ((long)(b - G_EDGE) * 256 + tid) * 8;
        const float dd = dis[base >> 6];
        const float4 a = *(const float4*)(x + base);
        const float4 c = *(const float4*)(x + base + 4);
        s16x8 o;
        o[0] = (short)f2bf(a.x * dd); o[1] = (short)f2bf(a.y * dd);
        o[2] = (short)f2bf(a.z * dd); o[3] = (short)f2bf(a.w * dd);
        o[4] = (short)f2bf(c.x * dd); o[5] = (short)f2bf(c.y * dd);
        o[6] = (short)f2bf(c.z * dd); o[7] = (short)f2bf(c.w * dd);
        *(s16x8*)(xb + base) = o;
    }
}

// ---- layer-1 aggregate in 64-dim input space (round-15 form) ----
__global__ __launch_bounds__(256) void agg64_kernel(const u16* __restrict__ xb,
                                                    const int* __restrict__ rp,
                                                    const int* __restrict__ blk,
                                                    const int* __restrict__ col,
                                                    const float* __restrict__ dis,
                                                    u16* __restrict__ aggX, int n) {
    const long t = (long)blockIdx.x * blockDim.x + threadIdx.x;
    const int lane = (int)(t & 31);
    const long i = t >> 5;
    if (i >= n) return;
    const int cl = lane & 7;
    const int eh = (lane >> 3) & 3;
    const int c = cl * 8;

    float acc[8] = {0, 0, 0, 0, 0, 0, 0, 0};
    if (eh == 0) {
        const s16x8 hv = *(const s16x8*)(xb + i * DIN + c);
#pragma unroll
        for (int q = 0; q < 8; ++q) acc[q] = bf2f((u16)hv[q]);
    }

    const int beg = rp[i] + blk[i >> 8];
    const int end = rp[i + 1] + blk[(int)(i + 1) >> 8];
    for (int e = beg + eh; e < end; e += 4) {
        const int s = col[e];
        const s16x8 v = *(const s16x8*)(xb + (long)s * DIN + c);
#pragma unroll
        for (int q = 0; q < 8; ++q) acc[q] += bf2f((u16)v[q]);
    }

#pragma unroll
    for (int q = 0; q < 8; ++q) acc[q] += __shfl_xor(acc[q], 8);
#pragma unroll
    for (int q = 0; q < 8; ++q) acc[q] += __shfl_xor(acc[q], 16);

    if (eh == 0 && (lane >> 4) == 0) {
        const float dd = dis[i];
        s16x8 ov;
#pragma unroll
        for (int q = 0; q < 8; ++q) ov[q] = (short)f2bf(acc[q] * dd);
        *(s16x8*)(aggX + i * DIN + c) = ov;
    }
}

// ---- MFMA GEMM, 128-row blocks, 32 rows/wave (2 A-tiles share each B-fragment) ----
// Epilogue: BN+ReLU->bf16 (layer1) OR dis-scale->int8+rowscale (layers 2/3).
template <int K, bool BN_EPI, bool QOUT>
__global__ __launch_bounds__(256) void gemm_mfma(const u16* __restrict__ A,   // [M][K]
                                                 const u16* __restrict__ Wt,  // [128][K]
                                                 const float* __restrict__ dis,
                                                 const float* __restrict__ scl,
                                                 const float* __restrict__ shf,
                                                 u16* __restrict__ C,         // bf16 out
                                                 signed char* __restrict__ Cq,// int8 out
                                                 float* __restrict__ qsc,     // row scales
                                                 int M) {
    __shared__ u16 ldsc[4][16][DH];
    const int wave = threadIdx.x >> 6;
    const int lane = threadIdx.x & 63;
    const int r16 = lane & 15;
    const int kc  = lane >> 4;
    const long row0 = (long)blockIdx.x * 128 + wave * 32;

    f32x4 acc[2][8];
#pragma unroll
    for (int h = 0; h < 2; ++h)
#pragma unroll
        for (int t = 0; t < 8; ++t)
#pragma unroll
            for (int q = 0; q < 4; ++q) acc[h][t][q] = 0.0f;

    long arow0 = row0 + r16;      if (arow0 >= M) arow0 = M - 1;
    long arow1 = row0 + 16 + r16; if (arow1 >= M) arow1 = M - 1;

#pragma unroll
    for (int ks = 0; ks < K; ks += 32) {
        const s16x8 a0 = *(const s16x8*)(A + arow0 * K + ks + kc * 8);
        const s16x8 a1 = *(const s16x8*)(A + arow1 * K + ks + kc * 8);
#pragma unroll
        for (int t = 0; t < 8; ++t) {
            const s16x8 b = *(const s16x8*)(Wt + (long)(t * 16 + r16) * K + ks + kc * 8);
            acc[0][t] = __builtin_amdgcn_mfma_f32_16x16x32_bf16(a0, b, acc[0][t], 0, 0, 0);
            acc[1][t] = __builtin_amdgcn_mfma_f32_16x16x32_bf16(a1, b, acc[1][t], 0, 0, 0);
        }
    }

    float scv[8], shv[8];
    if constexpr (BN_EPI) {
#pragma unroll
        for (int t = 0; t < 8; ++t) {
            scv[t] = scl[t * 16 + r16];
            shv[t] = shf[t * 16 + r16];
        }
    }

#pragma unroll
    for (int h = 0; h < 2; ++h) {
        const long rbase = row0 + h * 16;
        float dd[4];
        if constexpr (!BN_EPI) {
#pragma unroll
            for (int q = 0; q < 4; ++q) {
                long r = rbase + kc * 4 + q;
                dd[q] = dis[r < M ? r : (M - 1)];
            }
        }
        // stage to LDS, swizzled 16B blocks
#pragma unroll
        for (int t = 0; t < 8; ++t) {
            const int blkc = (t << 1) | (r16 >> 3);
            const int co = r16 & 7;
#pragma unroll
            for (int q = 0; q < 4; ++q) {
                const int row = kc * 4 + q;
                float y;
                if constexpr (BN_EPI) {
                    y = fmaxf(fmaf(acc[h][t][q], scv[t], shv[t]), 0.0f);
                } else {
                    y = acc[h][t][q] * dd[q];
                }
                ldsc[wave][row][(((blkc ^ (row & 7)) << 3) | co)] = f2bf(y);
            }
        }
        // read back rows coalesced; same-wave producer/consumer (in-order LDS pipe)
#pragma unroll
        for (int it = 0; it < 4; ++it) {
            const int rl = (lane >> 4) + it * 4;
            const long row = rbase + rl;
            const int phys = (lane & 15) ^ (rl & 7);
            const s16x8 v = *(const s16x8*)&ldsc[wave][rl][phys << 3];
            if constexpr (QOUT) {
                float f[8], m = 0.0f;
#pragma unroll
                for (int q = 0; q < 8; ++q) {
                    f[q] = bf2f((u16)v[q]);
                    m = fmaxf(m, fabsf(f[q]));
                }
                m = fmaxf(m, __shfl_xor(m, 1));
                m = fmaxf(m, __shfl_xor(m, 2));
                m = fmaxf(m, __shfl_xor(m, 4));
                m = fmaxf(m, __shfl_xor(m, 8));
                const float inv = (m > 0.0f) ? 127.0f / m : 0.0f;
                s8x8 o;
#pragma unroll
                for (int q = 0; q < 8; ++q) o[q] = (signed char)(int)rintf(f[q] * inv);
                if (row < M) {
                    *(s8x8*)(Cq + row * DH + ((lane & 15) << 3)) = o;
                    if ((lane & 15) == 0) qsc[row] = m * (1.0f / 127.0f);
                }
            } else {
                if (row < M) *(s16x8*)(C + row * DH + ((lane & 15) << 3)) = v;
            }
        }
    }
}

// ---- fused agg (int8 dequant): 32 lanes/node, 16 ch-lanes x 2 edge slots (round-15 form) ----
template <bool RES>
__global__ __launch_bounds__(256) void agg_epi_q8_kernel(const signed char* __restrict__ Hq,
                                                         const float* __restrict__ qsc,
                                                         const int* __restrict__ rp,
                                                         const int* __restrict__ blk,
                                                         const int* __restrict__ col,
                                                         const float* __restrict__ dis,
                                                         const float* __restrict__ scl,
                                                         const float* __restrict__ shf,
                                                         u16* __restrict__ out, int n) {
    const long t = (long)blockIdx.x * blockDim.x + threadIdx.x;
    const int lane = (int)(t & 31);
    const long i = t >> 5;
    if (i >= n) return;
    const int cl = lane & 15;
    const int eh = lane >> 4;
    const int c = cl * 8;

    float acc[8] = {0, 0, 0, 0, 0, 0, 0, 0};
    if (eh == 0) {   // self row (already dis[i]-scaled in gemm, int8)
        const s8x8 hv = *(const s8x8*)(Hq + i * DH + c);
        const float hs = qsc[i];
#pragma unroll
        for (int q = 0; q < 8; ++q) acc[q] = (float)hv[q] * hs;
    }

    const int beg = rp[i] + blk[i >> 8];
    const int end = rp[i + 1] + blk[(int)(i + 1) >> 8];
    for (int e = beg + eh; e < end; e += 2) {
        const int s = col[e];
        const float ss = qsc[s];
        const s8x8 v = *(const s8x8*)(Hq + (long)s * DH + c);
#pragma unroll
        for (int q = 0; q < 8; ++q) acc[q] = fmaf((float)v[q], ss, acc[q]);
    }

#pragma unroll
    for (int q = 0; q < 8; ++q) acc[q] += __shfl_xor(acc[q], 16);

    if (eh == 0) {
        const float dd = dis[i];
        const float4 s0 = *(const float4*)(scl + c);
        const float4 s1 = *(const float4*)(scl + c + 4);
        const float4 f0 = *(const float4*)(shf + c);
        const float4 f1 = *(const float4*)(shf + c + 4);
        const float sv[8] = {s0.x, s0.y, s0.z, s0.w, s1.x, s1.y, s1.z, s1.w};
        const float fv[8] = {f0.x, f0.y, f0.z, f0.w, f1.x, f1.y, f1.z, f1.w};

        float r[8];
#pragma unroll
        for (int q = 0; q < 8; ++q) r[q] = fmaxf(fmaf(acc[q] * dd, sv[q], fv[q]), 0.0f);
        if (RES) {
            const s16x8 rv = *(const s16x8*)(out + i * DH + c);
#pragma unroll
            for (int q = 0; q < 8; ++q) r[q] += bf2f((u16)rv[q]);
        }
        s16x8 ov;
#pragma unroll
        for (int q = 0; q < 8; ++q) ov[q] = (short)f2bf(r[q]);
        __builtin_nontemporal_store(ov, (s16x8*)(out + i * DH + c));
    }
}

// ------- fused mean-pool + MLP head: 1 block/graph -------
__global__ __launch_bounds__(256) void pool_head_kernel(const u16* __restrict__ h,
                                                        const int* __restrict__ gp,
                                                        const float* __restrict__ fc1w,
                                                        const float* __restrict__ fc1b,
                                                        const float* __restrict__ fc2w,
                                                        const float* __restrict__ fc2b,
                                                        float* __restrict__ out) {
    const int g = blockIdx.x;
    const int t = threadIdx.x;
    const int grp = t >> 4;
    const int cl = t & 15;
    const int c = cl * 8;
    const int beg = gp[g];
    const int end = gp[g + 1];

    float acc[8] = {0, 0, 0, 0, 0, 0, 0, 0};
    for (int i = beg + grp; i < end; i += 16) {
        const s16x8 v = *(const s16x8*)(h + (long)i * DH + c);
#pragma unroll
        for (int q = 0; q < 8; ++q) acc[q] += bf2f((u16)v[q]);
    }

    __shared__ float sm[16][DH];
    __shared__ float p[DH];
#pragma unroll
    for (int q = 0; q < 8; ++q) sm[grp][c + q] = acc[q];
    __syncthreads();

    if (t < DH) {
        float s = 0.0f;
#pragma unroll
        for (int r = 0; r < 16; ++r) s += sm[r][t];
        p[t] = s / fmaxf((float)(end - beg), 1.0f);
    }
    __syncthreads();

    if (t < 64) {
        float a = 0.0f;
#pragma unroll 4
        for (int k = 0; k < DH; ++k) a = fmaf(p[k], fc1w[(long)k * 64 + t], a);
        const float h1 = fmaxf(a + fc1b[t], 0.0f);
        float v = h1 * fc2w[t];
#pragma unroll
        for (int off = 32; off > 0; off >>= 1) v += __shfl_down(v, off);
        if (t == 0) out[g] = 1.0f / (1.0f + expf(-(v + fc2b[0])));
    }
}

// ---------------- launch ----------------
extern "C" void kernel_launch(void* const* d_in, const int* in_sizes, int n_in,
                              void* d_out, int out_size, void* d_ws, size_t ws_size,
                              hipStream_t stream) {
    const float* x     = (const float*)d_in[0];
    const int*   ei    = (const int*)d_in[1];
    const int*   batch = (const int*)d_in[2];
    const float* W1 = (const float*)d_in[3];
    const float* b1 = (const float*)d_in[4];
    const float* g1 = (const float*)d_in[5];
    const float* t1 = (const float*)d_in[6];
    const float* m1 = (const float*)d_in[7];
    const float* v1 = (const float*)d_in[8];
    const float* W2 = (const float*)d_in[9];
    const float* b2 = (const float*)d_in[10];
    const float* g2 = (const float*)d_in[11];
    const float* t2 = (const float*)d_in[12];
    const float* m2 = (const float*)d_in[13];
    const float* v2 = (const float*)d_in[14];
    const float* W3 = (const float*)d_in[15];
    const float* b3 = (const float*)d_in[16];
    const float* g3 = (const float*)d_in[17];
    const float* t3 = (const float*)d_in[18];
    const float* m3 = (const float*)d_in[19];
    const float* v3 = (const float*)d_in[20];
    const float* fc1w = (const float*)d_in[21];
    const float* fc1b = (const float*)d_in[22];
    const float* fc2w = (const float*)d_in[23];
    const float* fc2b = (const float*)d_in[24];

    const int* src = ei;
    const int* dst = ei + N_EDGES;

    // ---- workspace ----
    char* ws = (char*)d_ws;
    size_t off = 0;
    auto alloc = [&](size_t bytes) -> char* {
        char* p = ws + off;
        off = (off + bytes + 511) & ~(size_t)511;
        return p;
    };
    int*   deg     = (int*)  alloc((size_t)ZERO_INTS * 4);
    int*   cursor  = deg + N_NODES;
    int*   done    = deg + 2 * N_NODES;
    float* dis     = (float*)alloc((size_t)N_NODES * 4);
    int*   rp      = (int*)  alloc(((size_t)N_NODES + 1) * 4);
    int*   blk     = (int*)  alloc((size_t)N_SCAN_BLK * 4);
    int*   col     = (int*)  alloc((size_t)N_EDGES * 4);
    int*   gp      = (int*)  alloc((size_t)(NG + 1) * 4);
    float* bnsc    = (float*)alloc((size_t)3 * DH * 4);
    float* bnsh    = (float*)alloc((size_t)3 * DH * 4);
    u16*   Wt1     = (u16*)  alloc((size_t)DH * DIN * 2);
    u16*   Wt2     = (u16*)  alloc((size_t)DH * DH * 2);
    u16*   Wt3     = (u16*)  alloc((size_t)DH * DH * 2);
    u16*   xb      = (u16*)  alloc((size_t)N_NODES * DIN * 2);
    u16*   aggX    = (u16*)  alloc((size_t)N_NODES * DIN * 2);
    signed char* bufQ = (signed char*)alloc((size_t)N_NODES * DH);
    float* qscale  = (float*)alloc((size_t)N_NODES * 4);
    u16*   bufA    = (u16*)  alloc((size_t)N_NODES * DH * 2);

    const int TPB = 256;
    const int gZero = (ZERO_INTS / 4 + TPB - 1) / TPB;
    const int gGemm = (N_NODES + 127) / 128;                             // 782
    const int gAgg  = (int)(((long)N_NODES * 32 + TPB - 1) / TPB);       // 12500

    // ---- prep ----
    zero_kernel<<<gZero, TPB, 0, stream>>>(deg);
    degprep_kernel<<<PREP_TOTAL, TPB, 0, stream>>>(dst, deg, W1, Wt1, W2, Wt2, W3, Wt3,
                                                   b1, g1, t1, m1, v1,
                                                   b2, g2, t2, m2, v2,
                                                   b3, g3, t3, m3, v3,
                                                   bnsc, bnsh, batch, gp);
    scan_kernel<<<N_SCAN_BLK, SCAN_TPB, 0, stream>>>(deg, dis, rp, blk, done, N_NODES);
    csr_xcvt_kernel<<<CSRX_TOTAL, TPB, 0, stream>>>(src, dst, rp, blk, cursor, col,
                                                    x, dis, xb);

    // ---- layer 1: aggregate in 64-dim, then GEMM with BN+ReLU epilogue (bf16 out) ----
    agg64_kernel<<<gAgg, TPB, 0, stream>>>(xb, rp, blk, col, dis, aggX, N_NODES);
    gemm_mfma<DIN, true, false><<<gGemm, TPB, 0, stream>>>(aggX, Wt1, dis, bnsc, bnsh,
                                                           bufA, nullptr, nullptr, N_NODES);
    // ---- layer 2: GEMM -> int8+rowscale; gather-agg dequant (residual into bufA) ----
    gemm_mfma<DH, false, true><<<gGemm, TPB, 0, stream>>>(bufA, Wt2, dis, nullptr, nullptr,
                                                          nullptr, bufQ, qscale, N_NODES);
    agg_epi_q8_kernel<true><<<gAgg, TPB, 0, stream>>>(bufQ, qscale, rp, blk, col, dis,
                                                      bnsc + DH, bnsh + DH, bufA, N_NODES);
    // ---- layer 3 ----
    gemm_mfma<DH, false, true><<<gGemm, TPB, 0, stream>>>(bufA, Wt3, dis, nullptr, nullptr,
                                                          nullptr, bufQ, qscale, N_NODES);
    agg_epi_q8_kernel<false><<<gAgg, TPB, 0, stream>>>(bufQ, qscale, rp, blk, col, dis,
                                                       bnsc + 2 * DH, bnsh + 2 * DH, bufA,
                                                       N_NODES);

    // ---- pool + head (fused) ----
    pool_head_kernel<<<NG, TPB, 0, stream>>>(bufA, gp, fc1w, fc1b, fc2w, fc2b,
                                             (float*)d_out);
}

// Round 18
// 285.043 us; speedup vs baseline: 1.0659x; 1.0329x over previous
//
#include <hip/hip_runtime.h>
#include <math.h>

#define N_NODES 100000
#define N_EDGES 600000
#define DIN     64
#define DH      128
#define NG      512
#define EPS_BN  1e-5f
#define SCAN_TPB 256
#define N_SCAN_BLK ((N_NODES + SCAN_TPB - 1) / SCAN_TPB)   // 391
#define G_EDGE   ((N_EDGES + 255) / 256)                   // 2344

typedef unsigned short u16;
typedef short s16x8 __attribute__((ext_vector_type(8)));
typedef float f32x4 __attribute__((ext_vector_type(4)));
typedef int   i32x4 __attribute__((ext_vector_type(4)));
typedef signed char s8x8 __attribute__((ext_vector_type(8)));

__device__ __forceinline__ u16 f2bf(float x) {
    unsigned u = __builtin_bit_cast(unsigned, x);
    u += 0x7fffu + ((u >> 16) & 1u);   // round-to-nearest-even
    return (u16)(u >> 16);
}
__device__ __forceinline__ float bf2f(u16 h) {
    unsigned u = ((unsigned)h) << 16;
    return __builtin_bit_cast(float, u);
}

// ---------------- fast zero of deg|cursor|done ----------------
#define ZERO_INTS (2 * N_NODES + 256)
__global__ __launch_bounds__(256) void zero_kernel(int* __restrict__ p) {
    const int i = (blockIdx.x * 256 + threadIdx.x) * 4;
    if (i < ZERO_INTS) *(i32x4*)(p + i) = i32x4{0, 0, 0, 0};
}

// ------- merged: degree histogram | Wt1..3 | bn fold | graph bounds -------
#define PREP_WT1_BLKS  32
#define PREP_WT2_BLKS  64
#define PREP_WT3_BLKS  64
#define PREP_BN_BLKS   2
#define PREP_GB_BLKS   3
#define PREP_B0 G_EDGE
#define PREP_B1 (PREP_B0 + PREP_WT1_BLKS)
#define PREP_B2 (PREP_B1 + PREP_WT2_BLKS)
#define PREP_B3 (PREP_B2 + PREP_WT3_BLKS)
#define PREP_B4 (PREP_B3 + PREP_BN_BLKS)
#define PREP_TOTAL (PREP_B4 + PREP_GB_BLKS)

__device__ __forceinline__ void wt_body(const float* __restrict__ W, u16* __restrict__ Wt,
                                        int K, int idx) {
    if (idx >= K * DH) return;
    int k = idx / DH, n = idx % DH;
    Wt[(long)n * K + k] = f2bf(W[idx]);
}

__global__ __launch_bounds__(256) void degprep_kernel(
    const int* __restrict__ dst, int* __restrict__ deg,
    const float* __restrict__ W1, u16* __restrict__ Wt1,
    const float* __restrict__ W2, u16* __restrict__ Wt2,
    const float* __restrict__ W3, u16* __restrict__ Wt3,
    const float* b1, const float* g1, const float* bb1, const float* m1, const float* v1,
    const float* b2, const float* g2, const float* bb2, const float* m2, const float* v2,
    const float* b3, const float* g3, const float* bb3, const float* m3, const float* v3,
    float* __restrict__ sc, float* __restrict__ sh,
    const int* __restrict__ batch, int* __restrict__ gp) {
    const int b = blockIdx.x;
    const int tid = threadIdx.x;
    if (b < PREP_B0) {
        const int e = b * 256 + tid;
        if (e < N_EDGES) atomicAdd(&deg[dst[e]], 1);
    } else if (b < PREP_B1) {
        wt_body(W1, Wt1, DIN, (b - PREP_B0) * 256 + tid);
    } else if (b < PREP_B2) {
        wt_body(W2, Wt2, DH, (b - PREP_B1) * 256 + tid);
    } else if (b < PREP_B3) {
        wt_body(W3, Wt3, DH, (b - PREP_B2) * 256 + tid);
    } else if (b < PREP_B4) {
        const int i = (b - PREP_B3) * 256 + tid;
        if (i < 3 * DH) {
            int l = i >> 7, c = i & (DH - 1);
            const float* bc = l == 0 ? b1 : (l == 1 ? b2 : b3);
            const float* g  = l == 0 ? g1 : (l == 1 ? g2 : g3);
            const float* bb = l == 0 ? bb1 : (l == 1 ? bb2 : bb3);
            const float* m  = l == 0 ? m1 : (l == 1 ? m2 : m3);
            const float* v  = l == 0 ? v1 : (l == 1 ? v2 : v3);
            float s = g[c] * rsqrtf(v[c] + EPS_BN);
            sc[i] = s;
            sh[i] = (bc[c] - m[c]) * s + bb[c];
        }
    } else {
        const int g = (b - PREP_B4) * 256 + tid;
        if (g <= NG) {
            int lo = 0, hi = N_NODES;
            while (lo < hi) {
                int mid = (lo + hi) >> 1;
                if (batch[mid] < g) lo = mid + 1; else hi = mid;
            }
            gp[g] = lo;
        }
    }
}

// --- single-pass scan: local prefix + block sums; last-done block scans the block sums ---
__global__ __launch_bounds__(SCAN_TPB) void scan_kernel(const int* __restrict__ deg,
                                                        float* __restrict__ dis,
                                                        int* __restrict__ rp,
                                                        int* __restrict__ blk,
                                                        int* __restrict__ done, int n) {
    __shared__ int sm[SCAN_TPB];
    __shared__ int sflag;
    const int t = threadIdx.x;
    const int i = blockIdx.x * SCAN_TPB + t;
    int v = 0;
    if (i < n) {
        v = deg[i];
        dis[i] = rsqrtf((float)v + 1.0f);   // +1 self loop
    }
    sm[t] = v;
    __syncthreads();
#pragma unroll
    for (int off = 1; off < SCAN_TPB; off <<= 1) {
        int u = (t >= off) ? sm[t - off] : 0;
        __syncthreads();
        sm[t] += u;
        __syncthreads();
    }
    if (i <= n) rp[i] = sm[t] - v;            // local exclusive prefix
    if (t == SCAN_TPB - 1) blk[blockIdx.x] = sm[t];

    __syncthreads();
    if (t == 0) {
        __threadfence();
        const int r = atomicAdd(done, 1);
        sflag = (r == (int)gridDim.x - 1);
    }
    __syncthreads();
    if (!sflag) return;

    int a0 = (2 * t < N_SCAN_BLK)
                 ? __hip_atomic_load(&blk[2 * t], __ATOMIC_RELAXED, __HIP_MEMORY_SCOPE_AGENT)
                 : 0;
    int a1 = (2 * t + 1 < N_SCAN_BLK)
                 ? __hip_atomic_load(&blk[2 * t + 1], __ATOMIC_RELAXED, __HIP_MEMORY_SCOPE_AGENT)
                 : 0;
    const int s = a0 + a1;
    sm[t] = s;
    __syncthreads();
#pragma unroll
    for (int off = 1; off < SCAN_TPB; off <<= 1) {
        int u = (t >= off) ? sm[t - off] : 0;
        __syncthreads();
        sm[t] += u;
        __syncthreads();
    }
    const int ex = sm[t] - s;
    if (2 * t < N_SCAN_BLK) blk[2 * t] = ex;
    if (2 * t + 1 < N_SCAN_BLK) blk[2 * t + 1] = ex + a0;
}

// ---- merged: scatter edges into CSR (col only) | xcvt xb = bf16(x * dis[row]) ----
#define CSRX_XCVT_BLKS 3125
#define CSRX_TOTAL (G_EDGE + CSRX_XCVT_BLKS)
__global__ __launch_bounds__(256) void csr_xcvt_kernel(const int* __restrict__ src,
                                                       const int* __restrict__ dst,
                                                       const int* __restrict__ rp,
                                                       const int* __restrict__ blk,
                                                       int* __restrict__ cursor,
                                                       int* __restrict__ col,
                                                       const float* __restrict__ x,
                                                       const float* __restrict__ dis,
                                                       u16* __restrict__ xb) {
    const int b = blockIdx.x;
    const int tid = threadIdx.x;
    if (b < G_EDGE) {
        const int e = b * 256 + tid;
        if (e >= N_EDGES) return;
        const int s = src[e];
        const int d = dst[e];
        const int p = atomicAdd(&cursor[d], 1);
        col[rp[d] + blk[d >> 8] + p] = s;   // plain store: L2 write-combines the scatter
    } else {
        const long base = ((long)(b - G_EDGE) * 256 + tid) * 8;
        const float dd = dis[base >> 6];
        const float4 a = *(const float4*)(x + base);
        const float4 c = *(const float4*)(x + base + 4);
        s16x8 o;
        o[0] = (short)f2bf(a.x * dd); o[1] = (short)f2bf(a.y * dd);
        o[2] = (short)f2bf(a.z * dd); o[3] = (short)f2bf(a.w * dd);
        o[4] = (short)f2bf(c.x * dd); o[5] = (short)f2bf(c.y * dd);
        o[6] = (short)f2bf(c.z * dd); o[7] = (short)f2bf(c.w * dd);
        *(s16x8*)(xb + base) = o;
    }
}

// ---- layer-1 aggregate in 64-dim input space ----
__global__ __launch_bounds__(256) void agg64_kernel(const u16* __restrict__ xb,
                                                    const int* __restrict__ rp,
                                                    const int* __restrict__ blk,
                                                    const int* __restrict__ col,
                                                    const float* __restrict__ dis,
                                                    u16* __restrict__ aggX, int n) {
    const long t = (long)blockIdx.x * blockDim.x + threadIdx.x;
    const int lane = (int)(t & 31);
    const long i = t >> 5;
    if (i >= n) return;
    const int cl = lane & 7;
    const int eh = (lane >> 3) & 3;
    const int c = cl * 8;

    float acc[8] = {0, 0, 0, 0, 0, 0, 0, 0};
    if (eh == 0) {
        const s16x8 hv = *(const s16x8*)(xb + i * DIN + c);
#pragma unroll
        for (int q = 0; q < 8; ++q) acc[q] = bf2f((u16)hv[q]);
    }

    const int beg = rp[i] + blk[i >> 8];
    const int end = rp[i + 1] + blk[(int)(i + 1) >> 8];
    for (int e = beg + eh; e < end; e += 4) {
        const int s = col[e];
        const s16x8 v = *(const s16x8*)(xb + (long)s * DIN + c);
#pragma unroll
        for (int q = 0; q < 8; ++q) acc[q] += bf2f((u16)v[q]);
    }

#pragma unroll
    for (int q = 0; q < 8; ++q) acc[q] += __shfl_xor(acc[q], 8);
#pragma unroll
    for (int q = 0; q < 8; ++q) acc[q] += __shfl_xor(acc[q], 16);

    if (eh == 0 && (lane >> 4) == 0) {
        const float dd = dis[i];
        s16x8 ov;
#pragma unroll
        for (int q = 0; q < 8; ++q) ov[q] = (short)f2bf(acc[q] * dd);
        *(s16x8*)(aggX + i * DIN + c) = ov;
    }
}

// ---- MFMA GEMM, 128-row blocks, 32 rows/wave (2 A-tiles share each B-fragment) ----
// Epilogue: BN+ReLU->bf16 (layer1) OR dis-scale->int8+rowscale (layers 2/3).
template <int K, bool BN_EPI, bool QOUT>
__global__ __launch_bounds__(256) void gemm_mfma(const u16* __restrict__ A,   // [M][K]
                                                 const u16* __restrict__ Wt,  // [128][K]
                                                 const float* __restrict__ dis,
                                                 const float* __restrict__ scl,
                                                 const float* __restrict__ shf,
                                                 u16* __restrict__ C,         // bf16 out
                                                 signed char* __restrict__ Cq,// int8 out
                                                 float* __restrict__ qsc,     // row scales
                                                 int M) {
    __shared__ u16 ldsc[4][16][DH];
    const int wave = threadIdx.x >> 6;
    const int lane = threadIdx.x & 63;
    const int r16 = lane & 15;
    const int kc  = lane >> 4;
    const long row0 = (long)blockIdx.x * 128 + wave * 32;

    f32x4 acc[2][8];
#pragma unroll
    for (int h = 0; h < 2; ++h)
#pragma unroll
        for (int t = 0; t < 8; ++t)
#pragma unroll
            for (int q = 0; q < 4; ++q) acc[h][t][q] = 0.0f;

    long arow0 = row0 + r16;      if (arow0 >= M) arow0 = M - 1;
    long arow1 = row0 + 16 + r16; if (arow1 >= M) arow1 = M - 1;

#pragma unroll
    for (int ks = 0; ks < K; ks += 32) {
        const s16x8 a0 = *(const s16x8*)(A + arow0 * K + ks + kc * 8);
        const s16x8 a1 = *(const s16x8*)(A + arow1 * K + ks + kc * 8);
#pragma unroll
        for (int t = 0; t < 8; ++t) {
            const s16x8 b = *(const s16x8*)(Wt + (long)(t * 16 + r16) * K + ks + kc * 8);
            acc[0][t] = __builtin_amdgcn_mfma_f32_16x16x32_bf16(a0, b, acc[0][t], 0, 0, 0);
            acc[1][t] = __builtin_amdgcn_mfma_f32_16x16x32_bf16(a1, b, acc[1][t], 0, 0, 0);
        }
    }

    float scv[8], shv[8];
    if constexpr (BN_EPI) {
#pragma unroll
        for (int t = 0; t < 8; ++t) {
            scv[t] = scl[t * 16 + r16];
            shv[t] = shf[t * 16 + r16];
        }
    }

#pragma unroll
    for (int h = 0; h < 2; ++h) {
        const long rbase = row0 + h * 16;
        float dd[4];
        if constexpr (!BN_EPI) {
#pragma unroll
            for (int q = 0; q < 4; ++q) {
                long r = rbase + kc * 4 + q;
                dd[q] = dis[r < M ? r : (M - 1)];
            }
        }
        // stage to LDS, swizzled 16B blocks
#pragma unroll
        for (int t = 0; t < 8; ++t) {
            const int blkc = (t << 1) | (r16 >> 3);
            const int co = r16 & 7;
#pragma unroll
            for (int q = 0; q < 4; ++q) {
                const int row = kc * 4 + q;
                float y;
                if constexpr (BN_EPI) {
                    y = fmaxf(fmaf(acc[h][t][q], scv[t], shv[t]), 0.0f);
                } else {
                    y = acc[h][t][q] * dd[q];
                }
                ldsc[wave][row][(((blkc ^ (row & 7)) << 3) | co)] = f2bf(y);
            }
        }
        // read back rows coalesced; same-wave producer/consumer (in-order LDS pipe)
#pragma unroll
        for (int it = 0; it < 4; ++it) {
            const int rl = (lane >> 4) + it * 4;
            const long row = rbase + rl;
            const int phys = (lane & 15) ^ (rl & 7);
            const s16x8 v = *(const s16x8*)&ldsc[wave][rl][phys << 3];
            if constexpr (QOUT) {
                float f[8], m = 0.0f;
#pragma unroll
                for (int q = 0; q < 8; ++q) {
                    f[q] = bf2f((u16)v[q]);
                    m = fmaxf(m, fabsf(f[q]));
                }
                m = fmaxf(m, __shfl_xor(m, 1));
                m = fmaxf(m, __shfl_xor(m, 2));
                m = fmaxf(m, __shfl_xor(m, 4));
                m = fmaxf(m, __shfl_xor(m, 8));
                const float inv = (m > 0.0f) ? 127.0f / m : 0.0f;
                s8x8 o;
#pragma unroll
                for (int q = 0; q < 8; ++q) o[q] = (signed char)(int)rintf(f[q] * inv);
                if (row < M) {
                    *(s8x8*)(Cq + row * DH + ((lane & 15) << 3)) = o;
                    if ((lane & 15) == 0) qsc[row] = m * (1.0f / 127.0f);
                }
            } else {
                if (row < M) *(s16x8*)(C + row * DH + ((lane & 15) << 3)) = v;
            }
        }
    }
}

// ---- fused agg (int8 dequant): 32 lanes/node, 16 ch-lanes x 2 edge slots ----
template <bool RES>
__global__ __launch_bounds__(256) void agg_epi_q8_kernel(const signed char* __restrict__ Hq,
                                                         const float* __restrict__ qsc,
                                                         const int* __restrict__ rp,
                                                         const int* __restrict__ blk,
                                                         const int* __restrict__ col,
                                                         const float* __restrict__ dis,
                                                         const float* __restrict__ scl,
                                                         const float* __restrict__ shf,
                                                         u16* __restrict__ out, int n) {
    const long t = (long)blockIdx.x * blockDim.x + threadIdx.x;
    const int lane = (int)(t & 31);
    const long i = t >> 5;
    if (i >= n) return;
    const int cl = lane & 15;
    const int eh = lane >> 4;
    const int c = cl * 8;

    float acc[8] = {0, 0, 0, 0, 0, 0, 0, 0};
    if (eh == 0) {   // self row (already dis[i]-scaled in gemm, int8)
        const s8x8 hv = *(const s8x8*)(Hq + i * DH + c);
        const float hs = qsc[i];
#pragma unroll
        for (int q = 0; q < 8; ++q) acc[q] = (float)hv[q] * hs;
    }

    const int beg = rp[i] + blk[i >> 8];
    const int end = rp[i + 1] + blk[(int)(i + 1) >> 8];
    for (int e = beg + eh; e < end; e += 2) {
        const int s = col[e];
        const float ss = qsc[s];
        const s8x8 v = *(const s8x8*)(Hq + (long)s * DH + c);
#pragma unroll
        for (int q = 0; q < 8; ++q) acc[q] = fmaf((float)v[q], ss, acc[q]);
    }

#pragma unroll
    for (int q = 0; q < 8; ++q) acc[q] += __shfl_xor(acc[q], 16);

    if (eh == 0) {
        const float dd = dis[i];
        const float4 s0 = *(const float4*)(scl + c);
        const float4 s1 = *(const float4*)(scl + c + 4);
        const float4 f0 = *(const float4*)(shf + c);
        const float4 f1 = *(const float4*)(shf + c + 4);
        const float sv[8] = {s0.x, s0.y, s0.z, s0.w, s1.x, s1.y, s1.z, s1.w};
        const float fv[8] = {f0.x, f0.y, f0.z, f0.w, f1.x, f1.y, f1.z, f1.w};

        float r[8];
#pragma unroll
        for (int q = 0; q < 8; ++q) r[q] = fmaxf(fmaf(acc[q] * dd, sv[q], fv[q]), 0.0f);
        if (RES) {
            const s16x8 rv = *(const s16x8*)(out + i * DH + c);
#pragma unroll
            for (int q = 0; q < 8; ++q) r[q] += bf2f((u16)rv[q]);
        }
        s16x8 ov;
#pragma unroll
        for (int q = 0; q < 8; ++q) ov[q] = (short)f2bf(r[q]);
        __builtin_nontemporal_store(ov, (s16x8*)(out + i * DH + c));
    }
}

// ------- fused mean-pool + MLP head: 1 block/graph -------
__global__ __launch_bounds__(256) void pool_head_kernel(const u16* __restrict__ h,
                                                        const int* __restrict__ gp,
                                                        const float* __restrict__ fc1w,
                                                        const float* __restrict__ fc1b,
                                                        const float* __restrict__ fc2w,
                                                        const float* __restrict__ fc2b,
                                                        float* __restrict__ out) {
    const int g = blockIdx.x;
    const int t = threadIdx.x;
    const int grp = t >> 4;
    const int cl = t & 15;
    const int c = cl * 8;
    const int beg = gp[g];
    const int end = gp[g + 1];

    float acc[8] = {0, 0, 0, 0, 0, 0, 0, 0};
    for (int i = beg + grp; i < end; i += 16) {
        const s16x8 v = *(const s16x8*)(h + (long)i * DH + c);
#pragma unroll
        for (int q = 0; q < 8; ++q) acc[q] += bf2f((u16)v[q]);
    }

    __shared__ float sm[16][DH];
    __shared__ float p[DH];
#pragma unroll
    for (int q = 0; q < 8; ++q) sm[grp][c + q] = acc[q];
    __syncthreads();

    if (t < DH) {
        float s = 0.0f;
#pragma unroll
        for (int r = 0; r < 16; ++r) s += sm[r][t];
        p[t] = s / fmaxf((float)(end - beg), 1.0f);
    }
    __syncthreads();

    if (t < 64) {
        float a = 0.0f;
#pragma unroll 4
        for (int k = 0; k < DH; ++k) a = fmaf(p[k], fc1w[(long)k * 64 + t], a);
        const float h1 = fmaxf(a + fc1b[t], 0.0f);
        float v = h1 * fc2w[t];
#pragma unroll
        for (int off = 32; off > 0; off >>= 1) v += __shfl_down(v, off);
        if (t == 0) out[g] = 1.0f / (1.0f + expf(-(v + fc2b[0])));
    }
}

// ---------------- launch ----------------
extern "C" void kernel_launch(void* const* d_in, const int* in_sizes, int n_in,
                              void* d_out, int out_size, void* d_ws, size_t ws_size,
                              hipStream_t stream) {
    const float* x     = (const float*)d_in[0];
    const int*   ei    = (const int*)d_in[1];
    const int*   batch = (const int*)d_in[2];
    const float* W1 = (const float*)d_in[3];
    const float* b1 = (const float*)d_in[4];
    const float* g1 = (const float*)d_in[5];
    const float* t1 = (const float*)d_in[6];
    const float* m1 = (const float*)d_in[7];
    const float* v1 = (const float*)d_in[8];
    const float* W2 = (const float*)d_in[9];
    const float* b2 = (const float*)d_in[10];
    const float* g2 = (const float*)d_in[11];
    const float* t2 = (const float*)d_in[12];
    const float* m2 = (const float*)d_in[13];
    const float* v2 = (const float*)d_in[14];
    const float* W3 = (const float*)d_in[15];
    const float* b3 = (const float*)d_in[16];
    const float* g3 = (const float*)d_in[17];
    const float* t3 = (const float*)d_in[18];
    const float* m3 = (const float*)d_in[19];
    const float* v3 = (const float*)d_in[20];
    const float* fc1w = (const float*)d_in[21];
    const float* fc1b = (const float*)d_in[22];
    const float* fc2w = (const float*)d_in[23];
    const float* fc2b = (const float*)d_in[24];

    const int* src = ei;
    const int* dst = ei + N_EDGES;

    // ---- workspace ----
    char* ws = (char*)d_ws;
    size_t off = 0;
    auto alloc = [&](size_t bytes) -> char* {
        char* p = ws + off;
        off = (off + bytes + 511) & ~(size_t)511;
        return p;
    };
    int*   deg     = (int*)  alloc((size_t)ZERO_INTS * 4);
    int*   cursor  = deg + N_NODES;
    int*   done    = deg + 2 * N_NODES;
    float* dis     = (float*)alloc((size_t)N_NODES * 4);
    int*   rp      = (int*)  alloc(((size_t)N_NODES + 1) * 4);
    int*   blk     = (int*)  alloc((size_t)N_SCAN_BLK * 4);
    int*   col     = (int*)  alloc((size_t)N_EDGES * 4);
    int*   gp      = (int*)  alloc((size_t)(NG + 1) * 4);
    float* bnsc    = (float*)alloc((size_t)3 * DH * 4);
    float* bnsh    = (float*)alloc((size_t)3 * DH * 4);
    u16*   Wt1     = (u16*)  alloc((size_t)DH * DIN * 2);
    u16*   Wt2     = (u16*)  alloc((size_t)DH * DH * 2);
    u16*   Wt3     = (u16*)  alloc((size_t)DH * DH * 2);
    u16*   xb      = (u16*)  alloc((size_t)N_NODES * DIN * 2);
    u16*   aggX    = (u16*)  alloc((size_t)N_NODES * DIN * 2);
    signed char* bufQ = (signed char*)alloc((size_t)N_NODES * DH);
    float* qscale  = (float*)alloc((size_t)N_NODES * 4);
    u16*   bufA    = (u16*)  alloc((size_t)N_NODES * DH * 2);

    const int TPB = 256;
    const int gZero = (ZERO_INTS / 4 + TPB - 1) / TPB;
    const int gGemm = (N_NODES + 127) / 128;                             // 782
    const int gAgg  = (int)(((long)N_NODES * 32 + TPB - 1) / TPB);       // 12500

    // ---- prep ----
    zero_kernel<<<gZero, TPB, 0, stream>>>(deg);
    degprep_kernel<<<PREP_TOTAL, TPB, 0, stream>>>(dst, deg, W1, Wt1, W2, Wt2, W3, Wt3,
                                                   b1, g1, t1, m1, v1,
                                                   b2, g2, t2, m2, v2,
                                                   b3, g3, t3, m3, v3,
                                                   bnsc, bnsh, batch, gp);
    scan_kernel<<<N_SCAN_BLK, SCAN_TPB, 0, stream>>>(deg, dis, rp, blk, done, N_NODES);
    csr_xcvt_kernel<<<CSRX_TOTAL, TPB, 0, stream>>>(src, dst, rp, blk, cursor, col,
                                                    x, dis, xb);

    // ---- layer 1: aggregate in 64-dim, then GEMM with BN+ReLU epilogue (bf16 out) ----
    agg64_kernel<<<gAgg, TPB, 0, stream>>>(xb, rp, blk, col, dis, aggX, N_NODES);
    gemm_mfma<DIN, true, false><<<gGemm, TPB, 0, stream>>>(aggX, Wt1, dis, bnsc, bnsh,
                                                           bufA, nullptr, nullptr, N_NODES);
    // ---- layer 2: GEMM -> int8+rowscale; gather-agg dequant (residual into bufA) ----
    gemm_mfma<DH, false, true><<<gGemm, TPB, 0, stream>>>(bufA, Wt2, dis, nullptr, nullptr,
                                                          nullptr, bufQ, qscale, N_NODES);
    agg_epi_q8_kernel<true><<<gAgg, TPB, 0, stream>>>(bufQ, qscale, rp, blk, col, dis,
                                                      bnsc + DH, bnsh + DH, bufA, N_NODES);
    // ---- layer 3 ----
    gemm_mfma<DH, false, true><<<gGemm, TPB, 0, stream>>>(bufA, Wt3, dis, nullptr, nullptr,
                                                          nullptr, bufQ, qscale, N_NODES);
    agg_epi_q8_kernel<false><<<gAgg, TPB, 0, stream>>>(bufQ, qscale, rp, blk, col, dis,
                                                       bnsc + 2 * DH, bnsh + 2 * DH, bufA,
                                                       N_NODES);

    // ---- pool + head (fused) ----
    pool_head_kernel<<<NG, TPB, 0, stream>>>(bufA, gp, fc1w, fc1b, fc2w, fc2b,
                                             (float*)d_out);
}